// Round 7
// baseline (520.862 us; speedup 1.0000x reference)
//
#include <hip/hip_runtime.h>
#include <hip/hip_fp16.h>

#define N_NODES 50000
#define N_EDGES 100000
#define EDGE_DIM 8
#define EHID 32
#define DIN 32
#define H1 32
#define H2 64
#define NGRAPH 256
#define BN_EPS 1e-5f
#define KTOT 1056          // EHID*DIN + DIN (b2 rows appended as slice 32)
#define PREP_TOTAL ((H1 + H2) * KTOT)   // 101376
#define NB 256             // grid blocks (== #CUs -> co-residency guaranteed)
#define NTHR 512           // 8 waves/block

typedef __attribute__((ext_vector_type(8))) _Float16 f16x8;
typedef __attribute__((ext_vector_type(4))) float f32x4;
typedef unsigned int uint32;

// ---------------------------------------------------------------- utilities
__device__ inline void atomicMaxF(float* addr, float v) {
    if (v >= 0.0f) atomicMax((int*)addr, __float_as_int(v));
    else           atomicMin((unsigned int*)addr, __float_as_uint(v));
}

__device__ inline uint32 pk_f16(float a, float b) {
    uint32 r;
    asm("v_cvt_pkrtz_f16_f32 %0, %1, %2" : "=v"(r) : "v"(a), "v"(b));
    return r;
}

union GF { uint32 u[4]; f16x8 v; };

template <bool RELUG>
__device__ inline GF pack_g8(float4 a, float4 b) {
    if (RELUG) {
        a.x = fmaxf(a.x, 0.f); a.y = fmaxf(a.y, 0.f); a.z = fmaxf(a.z, 0.f); a.w = fmaxf(a.w, 0.f);
        b.x = fmaxf(b.x, 0.f); b.y = fmaxf(b.y, 0.f); b.z = fmaxf(b.z, 0.f); b.w = fmaxf(b.w, 0.f);
    }
    GF gf;
    gf.u[0] = pk_f16(a.x, a.y); gf.u[1] = pk_f16(a.z, a.w);
    gf.u[2] = pk_f16(b.x, b.y); gf.u[3] = pk_f16(b.z, b.w);
    return gf;
}

__device__ inline f16x8 mul_h(uint32 h, const GF& g) {
    GF r;
    asm("v_pk_mul_f16 %0, %1, %2" : "=v"(r.u[0]) : "v"(h), "v"(g.u[0]));
    asm("v_pk_mul_f16 %0, %1, %2" : "=v"(r.u[1]) : "v"(h), "v"(g.u[1]));
    asm("v_pk_mul_f16 %0, %1, %2" : "=v"(r.u[2]) : "v"(h), "v"(g.u[2]));
    asm("v_pk_mul_f16 %0, %1, %2" : "=v"(r.u[3]) : "v"(h), "v"(g.u[3]));
    return r.v;
}

// ---------------------------------------------------------------- grid barrier (all NB blocks co-resident)
__device__ __forceinline__ void gsync(unsigned* cnt, unsigned* gen) {
    __syncthreads();
    __threadfence();   // release: drain this block's global writes (wbl2 device scope)
    if (threadIdx.x == 0) {
        unsigned g = __hip_atomic_load(gen, __ATOMIC_ACQUIRE, __HIP_MEMORY_SCOPE_AGENT);
        unsigned my = __hip_atomic_fetch_add(cnt, 1u, __ATOMIC_ACQ_REL, __HIP_MEMORY_SCOPE_AGENT);
        if (my == NB - 1u) {
            __hip_atomic_store(cnt, 0u, __ATOMIC_RELAXED, __HIP_MEMORY_SCOPE_AGENT);
            __hip_atomic_fetch_add(gen, 1u, __ATOMIC_ACQ_REL, __HIP_MEMORY_SCOPE_AGENT);
        } else {
            while (__hip_atomic_load(gen, __ATOMIC_ACQUIRE, __HIP_MEMORY_SCOPE_AGENT) == g)
                __builtin_amdgcn_s_sleep(2);
        }
    }
    __syncthreads();
    __threadfence();   // acquire: invalidate caches before reading others' data
}

// ---------------------------------------------------------------- params
struct Params {
    const float *x, *edge_attr;
    const int *src, *dst, *batch;
    const float *e1w1, *e1b1, *e1w2, *e1b2, *root1, *bias1;
    const float *e2w1, *e2b1, *e2w2, *e2b2, *root2, *bias2;
    const float *h1w, *h1b, *bn1g, *bn1b, *bn1m, *bn1v;
    const float *h2w, *h2b, *bn2g, *bn2b, *bn2m, *bn2v, *h3w, *h3b;
    float *out;
    float *agg1, *agg2, *gmax, *gsum, *gcnt;
    unsigned short *w2h1, *w2h2;
    unsigned *bar_cnt, *bar_gen;
};

// ---------------------------------------------------------------- msg phase (device function)
// per block-iter: EPB edges; edge-MLP h computed in-block into LDS; each wave = one ot-tile
// of one 32-edge subchunk (2 chains of 16); B[33] f16 fragments in registers; atomic scatter.
template <int DOUT, bool RELUG>
__device__ void msg_phase(const float* __restrict__ gsrc, const float* __restrict__ eag,
                          const float* __restrict__ w1, const float* __restrict__ b1,
                          const int* __restrict__ src, const int* __restrict__ dst,
                          const unsigned short* __restrict__ w2h, float* __restrict__ agg,
                          char* smem, int tid, int bid)
{
    constexpr int NT  = DOUT / 16;   // 2 (H1) or 4 (H2)
    constexpr int EPB = 256 / NT;    // 128 or 64 edges per block-iter
    constexpr int KPT = EPB / 16;    // 8 or 4 h-values per thread

    float* w1s = (float*)smem;                        // [8][32]
    float* b1s = (float*)(smem + 1024);               // [32]
    uint32 (*hl)[36] = (uint32 (*)[36])(smem + 1280); // [EPB][36] dup-half2

    for (int i = tid; i < EDGE_DIM * EHID; i += NTHR) w1s[i] = w1[i];
    if (tid < EHID) b1s[tid] = b1[tid];

    const int wave = tid >> 6, lane = tid & 63;
    const int col = lane & 15, kq = lane >> 4;
    const int ot = wave & (NT - 1);
    const int sc = wave / NT;

    f16x8 B[33];
    {
        const unsigned short* bp = w2h + (size_t)(ot * 16 + col) * KTOT + kq * 8;
#pragma unroll
        for (int kk = 0; kk < 33; ++kk)
            B[kk] = *reinterpret_cast<const f16x8*>(bp + kk * 32);
    }

    const int e_loc = tid & (EPB - 1);
    const int kg = tid / EPB;
    const int NIT = (N_EDGES + EPB - 1) / EPB;

    for (int it = bid; it < NIT; it += NB) {
        const int ebase = it * EPB;
        __syncthreads();                 // prev-iter MFMA done; w1s/b1s ready (1st iter)
        // ---- edge-MLP: h[e][k] for this block's edges, into LDS
        {
            int e = ebase + e_loc;
            if (e < N_EDGES) {
                float4 a  = *reinterpret_cast<const float4*>(eag + (size_t)e * 8);
                float4 bq = *reinterpret_cast<const float4*>(eag + (size_t)e * 8 + 4);
                float ea[8] = {a.x, a.y, a.z, a.w, bq.x, bq.y, bq.z, bq.w};
                uint32 hv[KPT];
#pragma unroll
                for (int q = 0; q < KPT; ++q) {
                    int k = kg * KPT + q;
                    float acc = b1s[k];
#pragma unroll
                    for (int j = 0; j < 8; ++j) acc += ea[j] * w1s[j * EHID + k];
                    acc = fmaxf(acc, 0.f);
                    hv[q] = pk_f16(acc, acc);
                }
                if constexpr (KPT == 8) {
                    uint4 v0; v0.x = hv[0]; v0.y = hv[1]; v0.z = hv[2]; v0.w = hv[3];
                    uint4 v1; v1.x = hv[4]; v1.y = hv[5]; v1.z = hv[6]; v1.w = hv[7];
                    *reinterpret_cast<uint4*>(&hl[e_loc][kg * 8])     = v0;
                    *reinterpret_cast<uint4*>(&hl[e_loc][kg * 8 + 4]) = v1;
                } else {
                    uint4 v0; v0.x = hv[0]; v0.y = hv[1]; v0.z = hv[2]; v0.w = hv[3];
                    *reinterpret_cast<uint4*>(&hl[e_loc][kg * 4]) = v0;
                }
            }
        }
        __syncthreads();                 // h ready
        // ---- MFMA + scatter (32|N_EDGES -> subchunks are all-valid or all-invalid)
        const int ech = ebase + sc * 32;
        if (ech < N_EDGES) {
            const int eA = ech + col, eB = eA + 16;
            int sA = src[eA], sB = src[eB];
            float4 gA0 = *reinterpret_cast<const float4*>(gsrc + (size_t)sA * DIN + kq * 8);
            float4 gA1 = *reinterpret_cast<const float4*>(gsrc + (size_t)sA * DIN + kq * 8 + 4);
            float4 gB0 = *reinterpret_cast<const float4*>(gsrc + (size_t)sB * DIN + kq * 8);
            float4 gB1 = *reinterpret_cast<const float4*>(gsrc + (size_t)sB * DIN + kq * 8 + 4);
            GF gfA = pack_g8<RELUG>(gA0, gA1);
            GF gfB = pack_g8<RELUG>(gB0, gB1);

            const int hbA = sc * 32 + col, hbB = hbA + 16;
            f32x4 accA = (f32x4){0.f, 0.f, 0.f, 0.f};
            f32x4 accB = (f32x4){0.f, 0.f, 0.f, 0.f};
#pragma unroll
            for (int t = 0; t < 8; ++t) {
                uint4 ha = *reinterpret_cast<const uint4*>(&hl[hbA][t * 4]);
                uint4 hb = *reinterpret_cast<const uint4*>(&hl[hbB][t * 4]);
                accA = __builtin_amdgcn_mfma_f32_16x16x32_f16(mul_h(ha.x, gfA), B[t * 4 + 0], accA, 0, 0, 0);
                accB = __builtin_amdgcn_mfma_f32_16x16x32_f16(mul_h(hb.x, gfB), B[t * 4 + 0], accB, 0, 0, 0);
                accA = __builtin_amdgcn_mfma_f32_16x16x32_f16(mul_h(ha.y, gfA), B[t * 4 + 1], accA, 0, 0, 0);
                accB = __builtin_amdgcn_mfma_f32_16x16x32_f16(mul_h(hb.y, gfB), B[t * 4 + 1], accB, 0, 0, 0);
                accA = __builtin_amdgcn_mfma_f32_16x16x32_f16(mul_h(ha.z, gfA), B[t * 4 + 2], accA, 0, 0, 0);
                accB = __builtin_amdgcn_mfma_f32_16x16x32_f16(mul_h(hb.z, gfB), B[t * 4 + 2], accB, 0, 0, 0);
                accA = __builtin_amdgcn_mfma_f32_16x16x32_f16(mul_h(ha.w, gfA), B[t * 4 + 3], accA, 0, 0, 0);
                accB = __builtin_amdgcn_mfma_f32_16x16x32_f16(mul_h(hb.w, gfB), B[t * 4 + 3], accB, 0, 0, 0);
            }
            accA = __builtin_amdgcn_mfma_f32_16x16x32_f16(gfA.v, B[32], accA, 0, 0, 0);
            accB = __builtin_amdgcn_mfma_f32_16x16x32_f16(gfB.v, B[32], accB, 0, 0, 0);

            int4 ddA = *reinterpret_cast<const int4*>(dst + ech + kq * 4);
            int4 ddB = *reinterpret_cast<const int4*>(dst + ech + 16 + kq * 4);
            const int oc = ot * 16 + col;
            atomicAdd(&agg[(size_t)ddA.x * DOUT + oc], accA[0]);
            atomicAdd(&agg[(size_t)ddA.y * DOUT + oc], accA[1]);
            atomicAdd(&agg[(size_t)ddA.z * DOUT + oc], accA[2]);
            atomicAdd(&agg[(size_t)ddA.w * DOUT + oc], accA[3]);
            atomicAdd(&agg[(size_t)ddB.x * DOUT + oc], accB[0]);
            atomicAdd(&agg[(size_t)ddB.y * DOUT + oc], accB[1]);
            atomicAdd(&agg[(size_t)ddB.z * DOUT + oc], accB[2]);
            atomicAdd(&agg[(size_t)ddB.w * DOUT + oc], accB[3]);
        }
    }
}

// ---------------------------------------------------------------- mega kernel
__global__ __launch_bounds__(NTHR, 2) void mega_kernel(Params p)
{
    __shared__ __align__(16) char smem[19968];
    const int tid = threadIdx.x;
    const int bid = blockIdx.x;

    // ================ P0: prep =================
    // (a) w2+b2 -> f16 [DOUT][KTOT]
    for (int idx = bid * NTHR + tid; idx < PREP_TOTAL; idx += NB * NTHR) {
        const int n1 = H1 * KTOT;
        if (idx < n1) {
            int o = idx / KTOT, k = idx % KTOT;
            float v = (k < EHID * DIN) ? p.e1w2[(k >> 5) * (DIN * H1) + (k & 31) * H1 + o]
                                       : p.e1b2[(k - EHID * DIN) * H1 + o];
            p.w2h1[idx] = __half_as_ushort(__float2half(v));
        } else {
            int j = idx - n1;
            int o = j / KTOT, k = j % KTOT;
            float v = (k < EHID * DIN) ? p.e2w2[(k >> 5) * (DIN * H2) + (k & 31) * H2 + o]
                                       : p.e2b2[(k - EHID * DIN) * H2 + o];
            p.w2h2[j] = __half_as_ushort(__float2half(v));
        }
    }
    // (b) agg1 = x @ root1 + bias1
    {
        float* roots = (float*)smem;                          // 1024 f
        float (*ins)[33] = (float (*)[33])(smem + 4096);      // [16][33]
        for (int i = tid; i < DIN * H1; i += NTHR) roots[i] = p.root1[i];
        int o = tid & 31, nl = tid >> 5;
        float bo = p.bias1[o];
        for (int c = bid; c < N_NODES / 16; c += NB) {
            __syncthreads();
            for (int i = tid; i < 16 * DIN; i += NTHR)
                ins[i >> 5][i & 31] = p.x[(size_t)(c * 16 + (i >> 5)) * DIN + (i & 31)];
            __syncthreads();
            float t = bo;
#pragma unroll
            for (int i = 0; i < DIN; ++i) t += ins[nl][i] * roots[i * H1 + o];
            p.agg1[(size_t)(c * 16 + nl) * H1 + o] = t;
        }
    }
    // (c) agg2 = 0  (d) pool init
    {
        float4 z4 = {0.f, 0.f, 0.f, 0.f};
        for (int i = bid * NTHR + tid; i < N_NODES * H2 / 4; i += NB * NTHR)
            ((float4*)p.agg2)[i] = z4;
        for (int i = bid * NTHR + tid; i < NGRAPH * H2; i += NB * NTHR) {
            p.gmax[i] = __int_as_float(0xff800000u); p.gsum[i] = 0.f;
        }
        for (int i = bid * NTHR + tid; i < NGRAPH; i += NB * NTHR) p.gcnt[i] = 0.f;
    }
    gsync(p.bar_cnt, p.bar_gen);

    // ================ P1: msg layer 1 (into agg1) =================
    msg_phase<H1, false>(p.x, p.edge_attr, p.e1w1, p.e1b1, p.src, p.dst, p.w2h1, p.agg1, smem, tid, bid);
    gsync(p.bar_cnt, p.bar_gen);

    // ================ P2: msg layer 2 (g = relu(agg1), into agg2) =================
    msg_phase<H2, true>(p.agg1, p.edge_attr, p.e2w1, p.e2b1, p.src, p.dst, p.w2h2, p.agg2, smem, tid, bid);
    gsync(p.bar_cnt, p.bar_gen);

    // ================ P3: update2 + pool =================
    {
        float (*a1)[33] = (float (*)[33])smem;        // [64][33]
        float* r2 = (float*)(smem + 8448);            // [32*64]
        int* bt = (int*)(smem + 8448 + 8192);         // [64]
        for (int i = tid; i < DIN * H2; i += NTHR) r2[i] = p.root2[i];
        const int o = tid & 63, r = tid >> 6;
        float bo = p.bias2[o];
        const int NG = (N_NODES + 63) / 64;
        for (int g = bid; g < NG; g += NB) {
            int base = g * 64;
            __syncthreads();
            for (int i = tid; i < 64 * DIN; i += NTHR) {
                int nn = base + (i >> 5);
                a1[i >> 5][i & 31] = (nn < N_NODES) ? fmaxf(p.agg1[(size_t)nn * DIN + (i & 31)], 0.f) : 0.f;
            }
            if (tid < 64) bt[tid] = (base + tid < N_NODES) ? p.batch[base + tid] : -1;
            __syncthreads();
            int curb = -1; float s = 0.f, m = __int_as_float(0xff800000u), c = 0.f;
#pragma unroll
            for (int j = 0; j < 8; ++j) {
                int n = base + r * 8 + j;
                if (n >= N_NODES) break;
                int b = bt[r * 8 + j];
                if (b != curb) {
                    if (curb >= 0) {
                        atomicAdd(&p.gsum[curb * H2 + o], s);
                        atomicMaxF(&p.gmax[curb * H2 + o], m);
                        if (o == 0) atomicAdd(&p.gcnt[curb], c);
                    }
                    curb = b; s = 0.f; m = __int_as_float(0xff800000u); c = 0.f;
                }
                float v = bo + p.agg2[(size_t)n * H2 + o];
#pragma unroll
                for (int i = 0; i < DIN; ++i) v += a1[r * 8 + j][i] * r2[i * H2 + o];
                s += v; m = fmaxf(m, v); c += 1.f;
            }
            if (curb >= 0) {
                atomicAdd(&p.gsum[curb * H2 + o], s);
                atomicMaxF(&p.gmax[curb * H2 + o], m);
                if (o == 0) atomicAdd(&p.gcnt[curb], c);
            }
        }
    }
    gsync(p.bar_cnt, p.bar_gen);

    // ================ P4: head (block b = graph b) =================
    {
        float* feat = (float*)smem;            // 128
        float* z1s  = (float*)(smem + 512);    // 64
        float* z2s  = (float*)(smem + 768);    // 32
        const int b = bid;
        float cnt = fmaxf(p.gcnt[b], 1.f);
        __syncthreads();
        if (tid < H2)            feat[tid] = p.gmax[b * H2 + tid];
        else if (tid < 2 * H2)   feat[tid] = p.gsum[b * H2 + tid - H2] / cnt;
        __syncthreads();
        if (tid < H2) {
            float acc = p.h1b[tid];
#pragma unroll
            for (int j = 0; j < 2 * H2; ++j) acc += feat[j] * p.h1w[j * H2 + tid];
            acc = (acc - p.bn1m[tid]) * rsqrtf(p.bn1v[tid] + BN_EPS) * p.bn1g[tid] + p.bn1b[tid];
            z1s[tid] = fmaxf(acc, 0.f);
        }
        __syncthreads();
        if (tid < H2 / 2) {
            float acc = p.h2b[tid];
#pragma unroll
            for (int j = 0; j < H2; ++j) acc += z1s[j] * p.h2w[j * (H2 / 2) + tid];
            acc = (acc - p.bn2m[tid]) * rsqrtf(p.bn2v[tid] + BN_EPS) * p.bn2g[tid] + p.bn2b[tid];
            z2s[tid] = fmaxf(acc, 0.f);
        }
        __syncthreads();
        if (tid == 0) {
            float acc = p.h3b[0];
#pragma unroll
            for (int j = 0; j < H2 / 2; ++j) acc += z2s[j] * p.h3w[j];
            p.out[b] = acc;
        }
    }
}

// ---------------------------------------------------------------- launch
extern "C" void kernel_launch(void* const* d_in, const int* in_sizes, int n_in,
                              void* d_out, int out_size, void* d_ws, size_t ws_size,
                              hipStream_t stream)
{
    Params p;
    p.x         = (const float*)d_in[0];
    const int* ei = (const int*)d_in[1];
    p.edge_attr = (const float*)d_in[2];
    p.batch     = (const int*)d_in[3];
    p.e1w1 = (const float*)d_in[4];  p.e1b1 = (const float*)d_in[5];
    p.e1w2 = (const float*)d_in[6];  p.e1b2 = (const float*)d_in[7];
    p.root1 = (const float*)d_in[8]; p.bias1 = (const float*)d_in[9];
    p.e2w1 = (const float*)d_in[10]; p.e2b1 = (const float*)d_in[11];
    p.e2w2 = (const float*)d_in[12]; p.e2b2 = (const float*)d_in[13];
    p.root2 = (const float*)d_in[14]; p.bias2 = (const float*)d_in[15];
    p.h1w = (const float*)d_in[16]; p.h1b = (const float*)d_in[17];
    p.bn1g = (const float*)d_in[18]; p.bn1b = (const float*)d_in[19];
    p.bn1m = (const float*)d_in[20]; p.bn1v = (const float*)d_in[21];
    p.h2w = (const float*)d_in[22]; p.h2b = (const float*)d_in[23];
    p.bn2g = (const float*)d_in[24]; p.bn2b = (const float*)d_in[25];
    p.bn2m = (const float*)d_in[26]; p.bn2v = (const float*)d_in[27];
    p.h3w = (const float*)d_in[28]; p.h3b = (const float*)d_in[29];
    p.out = (float*)d_out;
    p.src = ei;
    p.dst = ei + N_EDGES;

    float* ws = (float*)d_ws;
    p.agg1 = ws;                                  // N*H1
    p.agg2 = p.agg1 + (size_t)N_NODES * H1;       // N*H2
    p.gmax = p.agg2 + (size_t)N_NODES * H2;       // NGRAPH*H2
    p.gsum = p.gmax + NGRAPH * H2;                // NGRAPH*H2
    p.gcnt = p.gsum + NGRAPH * H2;                // NGRAPH (+pad to 256)
    p.w2h1 = (unsigned short*)(p.gcnt + 256);     // H1*KTOT
    p.w2h2 = p.w2h1 + (size_t)H1 * KTOT;          // H2*KTOT
    uintptr_t bar_addr = ((uintptr_t)(p.w2h2 + (size_t)H2 * KTOT) + 63) & ~(uintptr_t)63;
    p.bar_cnt = (unsigned*)bar_addr;
    p.bar_gen = p.bar_cnt + 1;

    hipMemsetAsync((void*)bar_addr, 0, 8, stream);
    mega_kernel<<<dim3(NB), dim3(NTHR), 0, stream>>>(p);
}